// Round 10
// baseline (432.060 us; speedup 1.0000x reference)
//
#include <hip/hip_runtime.h>
#include <hip/hip_bf16.h>

#define DEVI __device__ __forceinline__

typedef unsigned short u16;
typedef __bf16 bf16x8 __attribute__((ext_vector_type(8)));
typedef float f32x4 __attribute__((ext_vector_type(4)));
typedef unsigned short u16x4 __attribute__((ext_vector_type(4)));
typedef unsigned short u16x8 __attribute__((ext_vector_type(8)));

DEVI float b2f(u16 u) {
    union { unsigned int i; float f; } x;
    x.i = ((unsigned int)u) << 16;
    return x.f;
}
DEVI u16 f2b(float f) {  // round-nearest-even f32 -> bf16
    union { float f; unsigned int i; } x;
    x.f = f;
    unsigned int r = x.i + 0x7fffu + ((x.i >> 16) & 1u);
    return (u16)(r >> 16);
}
DEVI float sigmoidf(float x) { return 1.f / (1.f + __expf(-x)); }
DEVI float tanh_fast(float x) { return 1.f - 2.f / (1.f + __expf(2.f * x)); }

DEVI float loadS(const void* base, int off, bool f32) {
    return f32 ? ((const float*)base)[off] : b2f(((const u16*)base)[off]);
}
DEVI void load8(const void* base, size_t off, bool f32, float w[8]) {
    if (f32) {
        const float* p = (const float*)base + off;
        const float4 a = *(const float4*)p, b = *(const float4*)(p + 4);
        w[0] = a.x; w[1] = a.y; w[2] = a.z; w[3] = a.w;
        w[4] = b.x; w[5] = b.y; w[6] = b.z; w[7] = b.w;
    } else {
        const u16x8 v = *(const u16x8*)((const u16*)base + off);
#pragma unroll
        for (int i = 0; i < 8; ++i) w[i] = b2f(v[i]);
    }
}

// Async global->LDS DMA, 16B per lane (wave-uniform LDS base + lane*16).
DEVI void gload16(const void* g, void* l) {
    __builtin_amdgcn_global_load_lds(
        (const __attribute__((address_space(1))) unsigned int*)g,
        (__attribute__((address_space(3))) unsigned int*)l, 16, 0, 0);
}

// ---------------------------------------------------------------------------
// ONE setup dispatch: weight convert (dtype self-detected per block) +
// per-group live-M-tile compaction lists (64-ROW tiles, round 10) +
// global dtype flag.
// ---------------------------------------------------------------------------
__global__ __launch_bounds__(512) void setup_all(const void* __restrict__ W1,
                                                 const void* __restrict__ W2,
                                                 const void* __restrict__ W3,
                                                 u16* __restrict__ Wc,
                                                 const int* __restrict__ length,
                                                 int nGroups, int mtc, int grpRows,
                                                 int* __restrict__ lists,
                                                 int* __restrict__ counts,
                                                 int* __restrict__ flag) {
    const int id = blockIdx.x, t = threadIdx.x;
    if (id < 896) {  // -------- weight convert with per-block dtype detect
        __shared__ int sf;
        if (t == 0) sf = 0;
        __syncthreads();
        const u16* p = (const u16*)W1;
        int bad = 0;
        for (int i = t; i < 1024; i += 512) {
            if (((p[i] >> 7) & 0xFF) >= 127) bad = 1;
        }
        if (bad) atomicOr(&sf, 1);
        __syncthreads();
        const bool f32 = sf != 0;
        const int idx = id * 512 + t;  // 458752 total
        const void* src;
        int off;
        if (idx < 65536) { src = W1; off = idx; }
        else if (idx < 327680) { src = W2; off = idx - 65536; }
        else { src = W3; off = idx - 327680; }
        Wc[idx] = f2b(loadS(src, off, f32));
    } else if (id < 896 + nGroups) {  // -------- live-tile list (64-row tiles)
        const int c = id - 896;
        __shared__ int arr[512];
        int f = 0;
        if (t < mtc) {
            const int gRow = c * grpRows + t * 64;
            f = ((gRow & 1023) < length[gRow >> 10]) ? 1 : 0;
        }
        arr[t] = f;
        __syncthreads();
        for (int off = 1; off < 512; off <<= 1) {
            const int v = (t >= off) ? arr[t - off] : 0;
            __syncthreads();
            arr[t] += v;
            __syncthreads();
        }
        if (f) lists[c * 512 + arr[t] - 1] = t;
        if (t == mtc - 1) counts[c] = arr[t];
    } else {  // -------- global dtype flag
        if (t == 0) *flag = 0;
        __syncthreads();
        const u16* p = (const u16*)W1;
        int bad = 0;
        for (int i = t; i < 1024; i += 512) {
            if (((p[i] >> 7) & 0xFF) >= 127) bad = 1;
        }
        if (bad) atomicOr(flag, 1);
    }
}

// ---------------------------------------------------------------------------
// FUSED 3-LAYER MLP, round 10: 64-ROW tiles (2 blocks/CU co-resident,
// 4 waves/SIMD — round 9's 1 block/CU at Occupancy 16% was the bottleneck)
// + operand-SWAPPED MFMA epilogues (lane holds 4 consecutive COLS at one
// row -> u16x4 vector h-writes instead of 128 scalar u16 writes; kills the
// quad-pair bank conflicts, 4.5M in round 9).
// Column ownership, ZERO K-loop barriers: wave w owns output cols
// [w*64,+64) (A/B) / [w*32,+32) (C); weight fragments private, loaded
// global->VGPR:  wf[i][ks] = W[(n0+i*16+r16)*K + k0+ks*32+quad*8 ..+8].
// Swapped-mfma D-map (operational rule from verified gemm_bt): for
// mfma(P,Q) lane(r16,quad) reg r holds D[p=quad*4+r][q=r16] — so
// mfma(wf,af) gives h[row=r16-block][col=quad*4+r-block]: 4 consecutive
// cols per lane. Hs: h [64][LDH=520] (pad 4 banks/row), A-panels staged
// in first 16 KB (dead before h1 write). LDS = 66,560 B.
// ---------------------------------------------------------------------------
#define LDH 520
#define LDE 264
__global__ __launch_bounds__(512, 4) void mlp_fused(const void* __restrict__ A,
                                                    const u16* __restrict__ Wc,
                                                    const void* __restrict__ b1,
                                                    const void* __restrict__ b2,
                                                    const void* __restrict__ b3,
                                                    u16* __restrict__ emb,
                                                    const int* __restrict__ lists,
                                                    const int* __restrict__ counts,
                                                    const int* __restrict__ flag) {
    const bool f32 = (*flag) != 0;
    const int cg = blockIdx.x >> 9;          // group (0..3)
    const int idx = blockIdx.x & 511;
    if (idx >= counts[cg]) return;           // dead tile (uniform exit)
    const int mt = lists[cg * 512 + idx];
    const size_t rowOff = (size_t)cg * 32768 + (size_t)mt * 64;

    const int tid = threadIdx.x;
    const int lane = tid & 63, w = tid >> 6;
    const int r16 = lane & 15, quad = lane >> 4;
    const int l3 = lane >> 3, l7 = lane & 7;
    const int swz = l7 ^ l3;

    __shared__ __align__(16) u16 Hs[64 * LDH];  // 66,560 B

    const u16* W1c = Wc;            // [512][128]
    const u16* W2c = Wc + 65536;    // [512][512]
    const u16* W3c = Wc + 327680;   // [256][512]

    // ---- stage state A-tile as two swizzled [64][64] panels (16 KB) --------
    if (f32) {
        const int srow = tid >> 3, sch = tid & 7;  // 64 rows x 8 chunks
#pragma unroll
        for (int kst = 0; kst < 2; ++kst) {
            const float* Af = (const float*)A + (rowOff + srow) * 128 + kst * 64 + sch * 8;
            const float4 a = *(const float4*)Af, b = *(const float4*)(Af + 4);
            u16x8 v;
            v[0] = f2b(a.x); v[1] = f2b(a.y); v[2] = f2b(a.z); v[3] = f2b(a.w);
            v[4] = f2b(b.x); v[5] = f2b(b.y); v[6] = f2b(b.z); v[7] = f2b(b.w);
            *(u16x8*)(&Hs[kst * 4096 + srow * 64 + ((sch ^ (srow & 7)) * 8)]) = v;
        }
    } else {
#pragma unroll
        for (int kst = 0; kst < 2; ++kst)  // wave w stages rows w*8..w*8+7
            gload16((const u16*)A + (rowOff + w * 8 + l3) * 128 + kst * 64 + swz * 8,
                    Hs + kst * 4096 + w * 512);
    }
    __syncthreads();

    f32x4 acc[4][4];

    // ---------------- phase A: h1 = relu(A @ W1^T + b1), K=128 --------------
#pragma unroll
    for (int mi = 0; mi < 4; ++mi)
#pragma unroll
        for (int i = 0; i < 4; ++i) acc[mi][i] = (f32x4){0.f, 0.f, 0.f, 0.f};

#pragma unroll
    for (int kst = 0; kst < 2; ++kst) {
        bf16x8 wf[4][2];
#pragma unroll
        for (int i = 0; i < 4; ++i)
#pragma unroll
            for (int ks = 0; ks < 2; ++ks)
                wf[i][ks] = *(const bf16x8*)(W1c + (size_t)(w * 64 + i * 16 + r16) * 128 +
                                             kst * 64 + ks * 32 + quad * 8);
#pragma unroll
        for (int mi = 0; mi < 4; ++mi) {
            bf16x8 af[2];
#pragma unroll
            for (int ks = 0; ks < 2; ++ks)
                af[ks] = *(const bf16x8*)&Hs[kst * 4096 + (mi * 16 + r16) * 64 +
                                             (((ks * 4 + quad) ^ (r16 & 7)) * 8)];
#pragma unroll
            for (int i = 0; i < 4; ++i)
#pragma unroll
                for (int ks = 0; ks < 2; ++ks)
                    acc[mi][i] = __builtin_amdgcn_mfma_f32_16x16x32_bf16(wf[i][ks], af[ks],
                                                                         acc[mi][i], 0, 0, 0);
        }
    }
    __syncthreads();  // all A-panel reads done before Hs overwrite

    // h1 write: row = mi*16 + r16, cols = w*64 + i*16 + quad*4 + (0..3)
    {
        float bv[4][4];
#pragma unroll
        for (int i = 0; i < 4; ++i)
#pragma unroll
            for (int r = 0; r < 4; ++r)
                bv[i][r] = loadS(b1, w * 64 + i * 16 + quad * 4 + r, f32);
#pragma unroll
        for (int mi = 0; mi < 4; ++mi)
#pragma unroll
            for (int i = 0; i < 4; ++i) {
                u16x4 v;
#pragma unroll
                for (int r = 0; r < 4; ++r)
                    v[r] = f2b(fmaxf(acc[mi][i][r] + bv[i][r], 0.f));
                *(u16x4*)(&Hs[(mi * 16 + r16) * LDH + w * 64 + i * 16 + quad * 4]) = v;
            }
    }
    __syncthreads();  // h1 visible

    // ---------------- phase B: h2 = relu(h1 @ W2^T + b2), K=512 -------------
#pragma unroll
    for (int mi = 0; mi < 4; ++mi)
#pragma unroll
        for (int i = 0; i < 4; ++i) acc[mi][i] = (f32x4){0.f, 0.f, 0.f, 0.f};

#pragma unroll 1
    for (int kst = 0; kst < 8; ++kst) {
        bf16x8 wf[4][2];
#pragma unroll
        for (int i = 0; i < 4; ++i)
#pragma unroll
            for (int ks = 0; ks < 2; ++ks)
                wf[i][ks] = *(const bf16x8*)(W2c + (size_t)(w * 64 + i * 16 + r16) * 512 +
                                             kst * 64 + ks * 32 + quad * 8);
#pragma unroll
        for (int mi = 0; mi < 4; ++mi) {
            bf16x8 af[2];
#pragma unroll
            for (int ks = 0; ks < 2; ++ks)
                af[ks] = *(const bf16x8*)&Hs[(mi * 16 + r16) * LDH + kst * 64 + ks * 32 +
                                             quad * 8];
#pragma unroll
            for (int i = 0; i < 4; ++i)
#pragma unroll
                for (int ks = 0; ks < 2; ++ks)
                    acc[mi][i] = __builtin_amdgcn_mfma_f32_16x16x32_bf16(wf[i][ks], af[ks],
                                                                         acc[mi][i], 0, 0, 0);
        }
    }
    __syncthreads();  // all h1 reads done before Hs overwrite

    // h2 write (same mapping as h1)
    {
        float bv[4][4];
#pragma unroll
        for (int i = 0; i < 4; ++i)
#pragma unroll
            for (int r = 0; r < 4; ++r)
                bv[i][r] = loadS(b2, w * 64 + i * 16 + quad * 4 + r, f32);
#pragma unroll
        for (int mi = 0; mi < 4; ++mi)
#pragma unroll
            for (int i = 0; i < 4; ++i) {
                u16x4 v;
#pragma unroll
                for (int r = 0; r < 4; ++r)
                    v[r] = f2b(fmaxf(acc[mi][i][r] + bv[i][r], 0.f));
                *(u16x4*)(&Hs[(mi * 16 + r16) * LDH + w * 64 + i * 16 + quad * 4]) = v;
            }
    }
    __syncthreads();  // h2 visible

    // ---------------- phase C: emb = h2 @ W3^T + b3, K=512, N=256 -----------
#pragma unroll
    for (int mi = 0; mi < 4; ++mi)
#pragma unroll
        for (int i = 0; i < 2; ++i) acc[mi][i] = (f32x4){0.f, 0.f, 0.f, 0.f};

#pragma unroll 1
    for (int kst = 0; kst < 8; ++kst) {
        bf16x8 wf[2][2];
#pragma unroll
        for (int i = 0; i < 2; ++i)
#pragma unroll
            for (int ks = 0; ks < 2; ++ks)
                wf[i][ks] = *(const bf16x8*)(W3c + (size_t)(w * 32 + i * 16 + r16) * 512 +
                                             kst * 64 + ks * 32 + quad * 8);
#pragma unroll
        for (int mi = 0; mi < 4; ++mi) {
            bf16x8 af[2];
#pragma unroll
            for (int ks = 0; ks < 2; ++ks)
                af[ks] = *(const bf16x8*)&Hs[(mi * 16 + r16) * LDH + kst * 64 + ks * 32 +
                                             quad * 8];
#pragma unroll
            for (int i = 0; i < 2; ++i)
#pragma unroll
                for (int ks = 0; ks < 2; ++ks)
                    acc[mi][i] = __builtin_amdgcn_mfma_f32_16x16x32_bf16(wf[i][ks], af[ks],
                                                                         acc[mi][i], 0, 0, 0);
        }
    }
    __syncthreads();  // all h2 reads done before epilogue staging

    // epilogue: emb[row=mi*16+r16][col=w*32+i*16+quad*4+r] -> Hs[LDE] -> global
    {
        float bv[2][4];
#pragma unroll
        for (int i = 0; i < 2; ++i)
#pragma unroll
            for (int r = 0; r < 4; ++r)
                bv[i][r] = loadS(b3, w * 32 + i * 16 + quad * 4 + r, f32);
#pragma unroll
        for (int mi = 0; mi < 4; ++mi)
#pragma unroll
            for (int i = 0; i < 2; ++i) {
                u16x4 v;
#pragma unroll
                for (int r = 0; r < 4; ++r) v[r] = f2b(acc[mi][i][r] + bv[i][r]);
                *(u16x4*)(&Hs[(mi * 16 + r16) * LDE + w * 32 + i * 16 + quad * 4]) = v;
            }
    }
    __syncthreads();
    const int orow = tid >> 5;          // 0..15
    const int ocol = (tid & 31) * 8;    // 0..248
#pragma unroll
    for (int p = 0; p < 4; ++p) {
        const int row = p * 16 + orow;
        *(u16x8*)(emb + (rowOff + row) * 256 + ocol) =
            *(const u16x8*)(&Hs[row * LDE + ocol]);
    }
}

// ---------------------------------------------------------------------------
// Fused flash-style attention (round-7 verified two-rows-per-load version).
// ---------------------------------------------------------------------------
__global__ __launch_bounds__(256) void attn_fused(const u16* __restrict__ emb,
                                                  const int* __restrict__ length,
                                                  const float* __restrict__ qt,
                                                  float* __restrict__ pm,
                                                  float* __restrict__ ps,
                                                  float* __restrict__ pws, int it) {
    const int b = blockIdx.x >> 3, slab = blockIdx.x & 7;
    const int lane = threadIdx.x & 63, wave = threadIdx.x >> 6;
    const int li = lane & 31, h = lane >> 5;
    const int len = length[b];
    const int row0 = slab * 128 + wave * 32;
    const int nr = min(32, max(0, len - row0));

    float qv[8];
#pragma unroll
    for (int k = 0; k < 8; ++k) qv[k] = 0.f;
    if (it != 0) {
        const float4 qa = *(const float4*)(qt + b * 256 + li * 8);
        const float4 qb = *(const float4*)(qt + b * 256 + li * 8 + 4);
        qv[0] = qa.x; qv[1] = qa.y; qv[2] = qa.z; qv[3] = qa.w;
        qv[4] = qb.x; qv[5] = qb.y; qv[6] = qb.z; qv[7] = qb.w;
    }
    const u16* eb = emb + ((size_t)(b * 1024 + row0)) * 256 + lane * 8;

    float m = -1e30f, s = 0.f;
    float a[8];
#pragma unroll
    for (int k = 0; k < 8; ++k) a[k] = 0.f;

    const int nch = (nr + 7) >> 3;
#pragma unroll 1
    for (int c = 0; c < nch; ++c) {
        const int rbase = c * 8;
        u16x8 v[4];
#pragma unroll
        for (int j = 0; j < 4; ++j)
            v[j] = *(const u16x8*)(eb + (size_t)(rbase + 2 * j) * 256);
        float pv[4];
        bool ok[4];
#pragma unroll
        for (int j = 0; j < 4; ++j) {
            float p = 0.f;
#pragma unroll
            for (int k = 0; k < 8; ++k) p += b2f(v[j][k]) * qv[k];
#pragma unroll
            for (int o = 16; o; o >>= 1) p += __shfl_xor(p, o, 64);
            ok[j] = (rbase + 2 * j + h < nr);
            pv[j] = ok[j] ? p : -1e30f;
        }
        const float cm = fmaxf(fmaxf(pv[0], pv[1]), fmaxf(pv[2], pv[3]));
        const float mn = fmaxf(m, cm);
        const float alpha = __expf(m - mn);
        float w[4], ssum = 0.f;
#pragma unroll
        for (int j = 0; j < 4; ++j) {
            w[j] = ok[j] ? __expf(pv[j] - mn) : 0.f;
            ssum += w[j];
        }
        s = s * alpha + ssum;
#pragma unroll
        for (int k = 0; k < 8; ++k) a[k] *= alpha;
#pragma unroll
        for (int j = 0; j < 4; ++j)
#pragma unroll
            for (int k = 0; k < 8; ++k) a[k] += w[j] * b2f(v[j][k]);
        m = mn;
    }

    const float om = __shfl_xor(m, 32, 64);
    const float M = fmaxf(m, om);
    const float sc = __expf(m - M);
    const float os = __shfl_xor(s, 32, 64);
    const float osc = __expf(om - M);
    const float S = s * sc + os * osc;
    float A[8];
#pragma unroll
    for (int k = 0; k < 8; ++k) {
        const float oa = __shfl_xor(a[k], 32, 64);
        A[k] = a[k] * sc + oa * osc;
    }

    const int pidx = b * 32 + slab * 4 + wave;
    if (lane == 0) { pm[pidx] = M; ps[pidx] = S; }
    if (lane < 32) {
        const float4 s0 = {A[0], A[1], A[2], A[3]};
        const float4 s1 = {A[4], A[5], A[6], A[7]};
        *(float4*)(pws + (size_t)pidx * 256 + li * 8) = s0;
        *(float4*)(pws + (size_t)pidx * 256 + li * 8 + 4) = s1;
    }
}

// Combine 32 partials into attended[t] for batch b (per-thread scalar).
DEVI float combine_att(const float* __restrict__ pm, const float* __restrict__ ps,
                       const float* __restrict__ pws, int b, int t) {
    float M = -1e30f;
#pragma unroll
    for (int p = 0; p < 32; ++p) M = fmaxf(M, pm[b * 32 + p]);
    float den = 0.f, acc = 0.f;
#pragma unroll
    for (int p = 0; p < 32; ++p) {
        const float sc = __expf(pm[b * 32 + p] - M);
        den += ps[b * 32 + p] * sc;
        acc += pws[(size_t)(b * 32 + p) * 256 + t] * sc;
    }
    return acc / den;
}

// ---------------------------------------------------------------------------
// Fused LSTM: attention-combine + gates GEMV + cell update (round-5 verified).
// ---------------------------------------------------------------------------
__global__ __launch_bounds__(256) void lstm_fused(const void* __restrict__ W_ih,
                                                  const void* __restrict__ W_hh,
                                                  const void* __restrict__ b_ih,
                                                  const void* __restrict__ b_hh,
                                                  const float* __restrict__ pm,
                                                  const float* __restrict__ ps,
                                                  const float* __restrict__ pws,
                                                  const float* __restrict__ qin,
                                                  float* __restrict__ qout,
                                                  float* __restrict__ ct,
                                                  const int* __restrict__ flag,
                                                  int it, void* __restrict__ out) {
    const bool f32 = (*flag) != 0;
    const int b = blockIdx.x >> 3, slab = blockIdx.x & 7;
    const int tid = threadIdx.x;
    const int lane = tid & 63, g = tid >> 6;  // wave = gate

    __shared__ float att[256];
    __shared__ float gsh[4][32];
    att[tid] = combine_att(pm, ps, pws, b, tid);
    __syncthreads();

    float sv[8];
    if (lane < 32) {
#pragma unroll
        for (int j = 0; j < 8; ++j) sv[j] = att[lane * 8 + j];
    } else if (it != 0) {
        const float* p = qin + b * 256 + (lane - 32) * 8;
        const float4 a = *(const float4*)p, c = *(const float4*)(p + 4);
        sv[0] = a.x; sv[1] = a.y; sv[2] = a.z; sv[3] = a.w;
        sv[4] = c.x; sv[5] = c.y; sv[6] = c.z; sv[7] = c.w;
    } else {
#pragma unroll
        for (int j = 0; j < 8; ++j) sv[j] = 0.f;
    }

    float r = 0.f;
#pragma unroll 4
    for (int oo = 0; oo < 32; ++oo) {
        const int o = g * 256 + slab * 32 + oo;
        float w[8];
        if (lane < 32) load8(W_ih, (size_t)o * 256 + lane * 8, f32, w);
        else load8(W_hh, (size_t)o * 256 + (lane - 32) * 8, f32, w);
        float p = 0.f;
#pragma unroll
        for (int j = 0; j < 8; ++j) p += w[j] * sv[j];
#pragma unroll
        for (int off = 32; off; off >>= 1) p += __shfl_xor(p, off, 64);
        if (lane == oo) r = p;
    }
    if (lane < 32) gsh[g][lane] = r;
    __syncthreads();

    if (tid < 32) {
        const int hidx = slab * 32 + tid;
        const float gi = gsh[0][tid] + loadS(b_ih, hidx, f32) + loadS(b_hh, hidx, f32);
        const float gf = gsh[1][tid] + loadS(b_ih, 256 + hidx, f32) +
                         loadS(b_hh, 256 + hidx, f32);
        const float gg = gsh[2][tid] + loadS(b_ih, 512 + hidx, f32) +
                         loadS(b_hh, 512 + hidx, f32);
        const float go = gsh[3][tid] + loadS(b_ih, 768 + hidx, f32) +
                         loadS(b_hh, 768 + hidx, f32);
        const float iv = sigmoidf(gi);
        const float fv = sigmoidf(gf);
        const float gv = tanh_fast(gg);
        const float ov = sigmoidf(go);
        const float cprev = (it != 0) ? ct[b * 256 + hidx] : 0.f;
        const float c = fv * cprev + iv * gv;
        const float h = ov * tanh_fast(c);
        ct[b * 256 + hidx] = c;
        qout[b * 256 + hidx] = h;
        if (it == 4) {
            if (f32) {
                float* o = (float*)out;
                o[b * 512 + hidx] = att[hidx];
                o[b * 512 + 256 + hidx] = h;
            } else {
                u16* o = (u16*)out;
                o[b * 512 + hidx] = f2b(att[hidx]);
                o[b * 512 + 256 + hidx] = f2b(h);
            }
        }
    }
}

// ---------------------------------------------------------------------------
extern "C" void kernel_launch(void* const* d_in, const int* in_sizes, int n_in,
                              void* d_out, int out_size, void* d_ws, size_t ws_size,
                              hipStream_t stream) {
    const void* state = d_in[0];
    const int* length = (const int*)d_in[1];
    const void* W1 = d_in[2];
    const void* b1 = d_in[3];
    const void* W2 = d_in[4];
    const void* b2 = d_in[5];
    const void* W3 = d_in[6];
    const void* b3 = d_in[7];
    const void* W_ih = d_in[8];
    const void* W_hh = d_in[9];
    const void* b_ih = d_in[10];
    const void* b_hh = d_in[11];

    if (ws_size < ((size_t)80 << 20)) return;  // diagnostic: absmax = 0.2988

    u16* emb = (u16*)d_ws;                     // 131072*256 bf16 = 67.1 MB
    u16* Wc = emb + (size_t)131072 * 256;      // 458752 u16 (bf16 MLP weights)
    float* qt0 = (float*)(Wc + 458752);        // 128*256 f32 (uninit ok; it0 guarded)
    float* ctb = qt0 + 32768;                  // 128*256 f32 (uninit ok; it0 guarded)
    float* qt1 = ctb + 32768;                  // 128*256 f32
    int* flag = (int*)(qt1 + 32768);           // 1 int (+3 pad)
    int* lists = flag + 4;                     // 4 groups x 512 ints
    int* counts = lists + 2048;                // 4 ints (+pad to 16)
    float* pm = (float*)(counts + 16);         // [4096]
    float* ps = pm + 4096;                     // [4096]
    float* pws = ps + 4096;                    // [4096,256] f32 (4 MB)

    // ONE setup dispatch: weight convert + 64-row live lists + dtype flag.
    hipLaunchKernelGGL(setup_all, dim3(901), dim3(512), 0, stream, W1, W2, W3, Wc,
                       length, 4, 512, 32768, lists, counts, flag);

    // ONE fused MLP dispatch: state -> emb; 2048 blocks (64-row tiles).
    hipLaunchKernelGGL(mlp_fused, dim3(2048), dim3(512), 0, stream, state, Wc,
                       b1, b2, b3, emb, lists, counts, flag);

    float* qswap[2] = {qt0, qt1};
    for (int it = 0; it < 5; ++it) {
        float* qin = qswap[it & 1];
        float* qout = qswap[(it & 1) ^ 1];
        hipLaunchKernelGGL(attn_fused, dim3(1024), dim3(256), 0, stream, emb, length, qin,
                           pm, ps, pws, it);
        hipLaunchKernelGGL(lstm_fused, dim3(1024), dim3(256), 0, stream, W_ih, W_hh,
                           b_ih, b_hh, pm, ps, pws, qin, qout, ctb, flag, it, d_out);
    }
}

// Round 12
// 400.518 us; speedup vs baseline: 1.0788x; 1.0788x over previous
//
#include <hip/hip_runtime.h>
#include <hip/hip_bf16.h>

#define DEVI __device__ __forceinline__

typedef unsigned short u16;
typedef __bf16 bf16x8 __attribute__((ext_vector_type(8)));
typedef float f32x4 __attribute__((ext_vector_type(4)));
typedef unsigned short u16x4 __attribute__((ext_vector_type(4)));
typedef unsigned short u16x8 __attribute__((ext_vector_type(8)));

DEVI float b2f(u16 u) {
    union { unsigned int i; float f; } x;
    x.i = ((unsigned int)u) << 16;
    return x.f;
}
DEVI u16 f2b(float f) {  // round-nearest-even f32 -> bf16
    union { float f; unsigned int i; } x;
    x.f = f;
    unsigned int r = x.i + 0x7fffu + ((x.i >> 16) & 1u);
    return (u16)(r >> 16);
}
DEVI float sigmoidf(float x) { return 1.f / (1.f + __expf(-x)); }
DEVI float tanh_fast(float x) { return 1.f - 2.f / (1.f + __expf(2.f * x)); }

DEVI float loadS(const void* base, int off, bool f32) {
    return f32 ? ((const float*)base)[off] : b2f(((const u16*)base)[off]);
}
DEVI void load8(const void* base, size_t off, bool f32, float w[8]) {
    if (f32) {
        const float* p = (const float*)base + off;
        const float4 a = *(const float4*)p, b = *(const float4*)(p + 4);
        w[0] = a.x; w[1] = a.y; w[2] = a.z; w[3] = a.w;
        w[4] = b.x; w[5] = b.y; w[6] = b.z; w[7] = b.w;
    } else {
        const u16x8 v = *(const u16x8*)((const u16*)base + off);
#pragma unroll
        for (int i = 0; i < 8; ++i) w[i] = b2f(v[i]);
    }
}

// Async global->LDS DMA, 16B per lane (wave-uniform LDS base + lane*16).
DEVI void gload16(const void* g, void* l) {
    __builtin_amdgcn_global_load_lds(
        (const __attribute__((address_space(1))) unsigned int*)g,
        (__attribute__((address_space(3))) unsigned int*)l, 16, 0, 0);
}

// ---------------------------------------------------------------------------
// ONE setup dispatch: weight convert (dtype self-detected per block) +
// per-group live-M-tile compaction lists (128-row tiles, round-9 layout) +
// global dtype flag.
// ---------------------------------------------------------------------------
__global__ __launch_bounds__(512) void setup_all(const void* __restrict__ W1,
                                                 const void* __restrict__ W2,
                                                 const void* __restrict__ W3,
                                                 u16* __restrict__ Wc,
                                                 const int* __restrict__ length,
                                                 int nGroups, int mtc, int grpRows,
                                                 int* __restrict__ lists,
                                                 int* __restrict__ counts,
                                                 int* __restrict__ flag) {
    const int id = blockIdx.x, t = threadIdx.x;
    if (id < 896) {  // -------- weight convert with per-block dtype detect
        __shared__ int sf;
        if (t == 0) sf = 0;
        __syncthreads();
        const u16* p = (const u16*)W1;
        int bad = 0;
        for (int i = t; i < 1024; i += 512) {
            if (((p[i] >> 7) & 0xFF) >= 127) bad = 1;
        }
        if (bad) atomicOr(&sf, 1);
        __syncthreads();
        const bool f32 = sf != 0;
        const int idx = id * 512 + t;  // 458752 total
        const void* src;
        int off;
        if (idx < 65536) { src = W1; off = idx; }
        else if (idx < 327680) { src = W2; off = idx - 65536; }
        else { src = W3; off = idx - 327680; }
        Wc[idx] = f2b(loadS(src, off, f32));
    } else if (id < 896 + nGroups) {  // -------- live-tile list (128-row tiles)
        const int c = id - 896;
        __shared__ int arr[512];
        int f = 0;
        if (t < mtc) {
            const int gRow = c * grpRows + t * 128;
            f = ((gRow & 1023) < length[gRow >> 10]) ? 1 : 0;
        }
        arr[t] = f;
        __syncthreads();
        for (int off = 1; off < 512; off <<= 1) {
            const int v = (t >= off) ? arr[t - off] : 0;
            __syncthreads();
            arr[t] += v;
            __syncthreads();
        }
        if (f) lists[c * 512 + arr[t] - 1] = t;
        if (t == mtc - 1) counts[c] = arr[t];
    } else {  // -------- global dtype flag
        if (t == 0) *flag = 0;
        __syncthreads();
        const u16* p = (const u16*)W1;
        int bad = 0;
        for (int i = t; i < 1024; i += 512) {
            if (((p[i] >> 7) & 0xFF) >= 127) bad = 1;
        }
        if (bad) atomicOr(flag, 1);
    }
}

// ---------------------------------------------------------------------------
// FUSED 3-LAYER MLP, round 11 = round 9 structure (128-row tiles, 1 blk/CU,
// weight fetched once/block, 8-mi ILP — round 10's 64-row tiles regressed)
// + round 10's VERIFIED swapped-operand MFMA epilogues (lane holds 4
// consecutive COLS at one row -> u16x4 h-writes; round 9's scalar u16
// epilogue writes were the 4.5M 4-way bank conflicts)
// + #pragma unroll 2 on phase B/C kst loops (L2 weight-load latency was the
// 30us-vs-14us/block gap at 2 waves/SIMD; unroll lets the scheduler issue
// kst+1's 8 independent loads under kst's 64 MFMAs).
// Column ownership, ZERO K-loop barriers (wave w owns output cols; weight
// fragments private, global->VGPR). Hs = [128][LDH=520] h tiles, A-panels
// staged in first 32 KB (dead before h1 write). LDS = 133,120 B.
// Swapped-mfma D-map (round-10-verified): mfma(wf, af) lane(r16,quad) reg r
// holds h[row = mi*16 + r16][col = base + quad*4 + r].
// ---------------------------------------------------------------------------
#define LDH 520
#define LDE 264
__global__ __launch_bounds__(512, 2) void mlp_fused(const void* __restrict__ A,
                                                    const u16* __restrict__ Wc,
                                                    const void* __restrict__ b1,
                                                    const void* __restrict__ b2,
                                                    const void* __restrict__ b3,
                                                    u16* __restrict__ emb,
                                                    const int* __restrict__ lists,
                                                    const int* __restrict__ counts,
                                                    const int* __restrict__ flag) {
    const bool f32 = (*flag) != 0;
    const int cg = blockIdx.x >> 9;          // group (0..1)
    const int idx = blockIdx.x & 511;
    if (idx >= counts[cg]) return;           // dead tile (uniform exit)
    const int mt = lists[cg * 512 + idx];
    const size_t rowOff = (size_t)cg * 65536 + (size_t)mt * 128;

    const int tid = threadIdx.x;
    const int lane = tid & 63, w = tid >> 6;
    const int r16 = lane & 15, quad = lane >> 4;
    const int l3 = lane >> 3, l7 = lane & 7;
    const int swz = l7 ^ l3;

    __shared__ __align__(16) u16 Hs[128 * LDH];  // 133,120 B

    const u16* W1c = Wc;            // [512][128]
    const u16* W2c = Wc + 65536;    // [512][512]
    const u16* W3c = Wc + 327680;   // [256][512]

    // ---- stage state A-tile as two swizzled [128][64] panels (32 KB) -------
    if (f32) {
        const int srow = tid >> 3, sch = tid & 7;
#pragma unroll
        for (int kst = 0; kst < 2; ++kst)
#pragma unroll
            for (int p = 0; p < 2; ++p) {
                const int row = p * 64 + srow;
                const float* Af =
                    (const float*)A + (rowOff + row) * 128 + kst * 64 + sch * 8;
                const float4 a = *(const float4*)Af, b = *(const float4*)(Af + 4);
                u16x8 v;
                v[0] = f2b(a.x); v[1] = f2b(a.y); v[2] = f2b(a.z); v[3] = f2b(a.w);
                v[4] = f2b(b.x); v[5] = f2b(b.y); v[6] = f2b(b.z); v[7] = f2b(b.w);
                *(u16x8*)(&Hs[kst * 8192 + row * 64 + ((sch ^ (row & 7)) * 8)]) = v;
            }
    } else {
#pragma unroll
        for (int kst = 0; kst < 2; ++kst)
#pragma unroll
            for (int p = 0; p < 2; ++p) {
                const int seg = p * 8 + w;  // wave-uniform 1KB LDS segment
                gload16((const u16*)A + (rowOff + seg * 8 + l3) * 128 + kst * 64 + swz * 8,
                        Hs + kst * 8192 + seg * 512);
            }
    }
    __syncthreads();

    f32x4 acc[8][4];

    // ---------------- phase A: h1 = relu(A @ W1^T + b1), K=128 --------------
#pragma unroll
    for (int mi = 0; mi < 8; ++mi)
#pragma unroll
        for (int i = 0; i < 4; ++i) acc[mi][i] = (f32x4){0.f, 0.f, 0.f, 0.f};

#pragma unroll
    for (int kst = 0; kst < 2; ++kst) {
        bf16x8 wf[4][2];
#pragma unroll
        for (int i = 0; i < 4; ++i)
#pragma unroll
            for (int ks = 0; ks < 2; ++ks)
                wf[i][ks] = *(const bf16x8*)(W1c + (size_t)(w * 64 + i * 16 + r16) * 128 +
                                             kst * 64 + ks * 32 + quad * 8);
#pragma unroll
        for (int mi = 0; mi < 8; ++mi) {
            bf16x8 af[2];
#pragma unroll
            for (int ks = 0; ks < 2; ++ks)
                af[ks] = *(const bf16x8*)&Hs[kst * 8192 + (mi * 16 + r16) * 64 +
                                             (((ks * 4 + quad) ^ (r16 & 7)) * 8)];
#pragma unroll
            for (int i = 0; i < 4; ++i)
#pragma unroll
                for (int ks = 0; ks < 2; ++ks)
                    acc[mi][i] = __builtin_amdgcn_mfma_f32_16x16x32_bf16(wf[i][ks], af[ks],
                                                                         acc[mi][i], 0, 0, 0);
        }
    }
    __syncthreads();  // all A-panel reads done before Hs overwrite

    // h1 write: row = mi*16 + r16, cols = w*64 + i*16 + quad*4 + (0..3)
    {
        float bv[4][4];
#pragma unroll
        for (int i = 0; i < 4; ++i)
#pragma unroll
            for (int r = 0; r < 4; ++r)
                bv[i][r] = loadS(b1, w * 64 + i * 16 + quad * 4 + r, f32);
#pragma unroll
        for (int mi = 0; mi < 8; ++mi)
#pragma unroll
            for (int i = 0; i < 4; ++i) {
                u16x4 v;
#pragma unroll
                for (int r = 0; r < 4; ++r)
                    v[r] = f2b(fmaxf(acc[mi][i][r] + bv[i][r], 0.f));
                *(u16x4*)(&Hs[(mi * 16 + r16) * LDH + w * 64 + i * 16 + quad * 4]) = v;
            }
    }
    __syncthreads();  // h1 visible

    // ---------------- phase B: h2 = relu(h1 @ W2^T + b2), K=512 -------------
#pragma unroll
    for (int mi = 0; mi < 8; ++mi)
#pragma unroll
        for (int i = 0; i < 4; ++i) acc[mi][i] = (f32x4){0.f, 0.f, 0.f, 0.f};

#pragma unroll 2
    for (int kst = 0; kst < 8; ++kst) {
        bf16x8 wf[4][2];
#pragma unroll
        for (int i = 0; i < 4; ++i)
#pragma unroll
            for (int ks = 0; ks < 2; ++ks)
                wf[i][ks] = *(const bf16x8*)(W2c + (size_t)(w * 64 + i * 16 + r16) * 512 +
                                             kst * 64 + ks * 32 + quad * 8);
#pragma unroll
        for (int mi = 0; mi < 8; ++mi) {
            bf16x8 af[2];
#pragma unroll
            for (int ks = 0; ks < 2; ++ks)
                af[ks] = *(const bf16x8*)&Hs[(mi * 16 + r16) * LDH + kst * 64 + ks * 32 +
                                             quad * 8];
#pragma unroll
            for (int i = 0; i < 4; ++i)
#pragma unroll
                for (int ks = 0; ks < 2; ++ks)
                    acc[mi][i] = __builtin_amdgcn_mfma_f32_16x16x32_bf16(wf[i][ks], af[ks],
                                                                         acc[mi][i], 0, 0, 0);
        }
    }
    __syncthreads();  // all h1 reads done before Hs overwrite

    // h2 write (same mapping as h1)
    {
        float bv[4][4];
#pragma unroll
        for (int i = 0; i < 4; ++i)
#pragma unroll
            for (int r = 0; r < 4; ++r)
                bv[i][r] = loadS(b2, w * 64 + i * 16 + quad * 4 + r, f32);
#pragma unroll
        for (int mi = 0; mi < 8; ++mi)
#pragma unroll
            for (int i = 0; i < 4; ++i) {
                u16x4 v;
#pragma unroll
                for (int r = 0; r < 4; ++r)
                    v[r] = f2b(fmaxf(acc[mi][i][r] + bv[i][r], 0.f));
                *(u16x4*)(&Hs[(mi * 16 + r16) * LDH + w * 64 + i * 16 + quad * 4]) = v;
            }
    }
    __syncthreads();  // h2 visible

    // ---------------- phase C: emb = h2 @ W3^T + b3, K=512, N=256 -----------
#pragma unroll
    for (int mi = 0; mi < 8; ++mi)
#pragma unroll
        for (int i = 0; i < 2; ++i) acc[mi][i] = (f32x4){0.f, 0.f, 0.f, 0.f};

#pragma unroll 2
    for (int kst = 0; kst < 8; ++kst) {
        bf16x8 wf[2][2];
#pragma unroll
        for (int i = 0; i < 2; ++i)
#pragma unroll
            for (int ks = 0; ks < 2; ++ks)
                wf[i][ks] = *(const bf16x8*)(W3c + (size_t)(w * 32 + i * 16 + r16) * 512 +
                                             kst * 64 + ks * 32 + quad * 8);
#pragma unroll
        for (int mi = 0; mi < 8; ++mi) {
            bf16x8 af[2];
#pragma unroll
            for (int ks = 0; ks < 2; ++ks)
                af[ks] = *(const bf16x8*)&Hs[(mi * 16 + r16) * LDH + kst * 64 + ks * 32 +
                                             quad * 8];
#pragma unroll
            for (int i = 0; i < 2; ++i)
#pragma unroll
                for (int ks = 0; ks < 2; ++ks)
                    acc[mi][i] = __builtin_amdgcn_mfma_f32_16x16x32_bf16(wf[i][ks], af[ks],
                                                                         acc[mi][i], 0, 0, 0);
        }
    }
    __syncthreads();  // all h2 reads done before epilogue staging

    // epilogue: emb[row=mi*16+r16][col=w*32+i*16+quad*4+r] -> Hs[LDE] -> global
    {
        float bv[2][4];
#pragma unroll
        for (int i = 0; i < 2; ++i)
#pragma unroll
            for (int r = 0; r < 4; ++r)
                bv[i][r] = loadS(b3, w * 32 + i * 16 + quad * 4 + r, f32);
#pragma unroll
        for (int mi = 0; mi < 8; ++mi)
#pragma unroll
            for (int i = 0; i < 2; ++i) {
                u16x4 v;
#pragma unroll
                for (int r = 0; r < 4; ++r) v[r] = f2b(acc[mi][i][r] + bv[i][r]);
                *(u16x4*)(&Hs[(mi * 16 + r16) * LDE + w * 32 + i * 16 + quad * 4]) = v;
            }
    }
    __syncthreads();
    const int orow = tid >> 5;          // 0..15
    const int ocol = (tid & 31) * 8;    // 0..248
#pragma unroll
    for (int p = 0; p < 8; ++p) {
        const int row = p * 16 + orow;
        *(u16x8*)(emb + (rowOff + row) * 256 + ocol) =
            *(const u16x8*)(&Hs[row * LDE + ocol]);
    }
}

// ---------------------------------------------------------------------------
// Fused flash-style attention (round-7 verified two-rows-per-load version).
// ---------------------------------------------------------------------------
__global__ __launch_bounds__(256) void attn_fused(const u16* __restrict__ emb,
                                                  const int* __restrict__ length,
                                                  const float* __restrict__ qt,
                                                  float* __restrict__ pm,
                                                  float* __restrict__ ps,
                                                  float* __restrict__ pws, int it) {
    const int b = blockIdx.x >> 3, slab = blockIdx.x & 7;
    const int lane = threadIdx.x & 63, wave = threadIdx.x >> 6;
    const int li = lane & 31, h = lane >> 5;
    const int len = length[b];
    const int row0 = slab * 128 + wave * 32;
    const int nr = min(32, max(0, len - row0));

    float qv[8];
#pragma unroll
    for (int k = 0; k < 8; ++k) qv[k] = 0.f;
    if (it != 0) {
        const float4 qa = *(const float4*)(qt + b * 256 + li * 8);
        const float4 qb = *(const float4*)(qt + b * 256 + li * 8 + 4);
        qv[0] = qa.x; qv[1] = qa.y; qv[2] = qa.z; qv[3] = qa.w;
        qv[4] = qb.x; qv[5] = qb.y; qv[6] = qb.z; qv[7] = qb.w;
    }
    const u16* eb = emb + ((size_t)(b * 1024 + row0)) * 256 + lane * 8;

    float m = -1e30f, s = 0.f;
    float a[8];
#pragma unroll
    for (int k = 0; k < 8; ++k) a[k] = 0.f;

    const int nch = (nr + 7) >> 3;
#pragma unroll 1
    for (int c = 0; c < nch; ++c) {
        const int rbase = c * 8;
        u16x8 v[4];
#pragma unroll
        for (int j = 0; j < 4; ++j)
            v[j] = *(const u16x8*)(eb + (size_t)(rbase + 2 * j) * 256);
        float pv[4];
        bool ok[4];
#pragma unroll
        for (int j = 0; j < 4; ++j) {
            float p = 0.f;
#pragma unroll
            for (int k = 0; k < 8; ++k) p += b2f(v[j][k]) * qv[k];
#pragma unroll
            for (int o = 16; o; o >>= 1) p += __shfl_xor(p, o, 64);
            ok[j] = (rbase + 2 * j + h < nr);
            pv[j] = ok[j] ? p : -1e30f;
        }
        const float cm = fmaxf(fmaxf(pv[0], pv[1]), fmaxf(pv[2], pv[3]));
        const float mn = fmaxf(m, cm);
        const float alpha = __expf(m - mn);
        float w[4], ssum = 0.f;
#pragma unroll
        for (int j = 0; j < 4; ++j) {
            w[j] = ok[j] ? __expf(pv[j] - mn) : 0.f;
            ssum += w[j];
        }
        s = s * alpha + ssum;
#pragma unroll
        for (int k = 0; k < 8; ++k) a[k] *= alpha;
#pragma unroll
        for (int j = 0; j < 4; ++j)
#pragma unroll
            for (int k = 0; k < 8; ++k) a[k] += w[j] * b2f(v[j][k]);
        m = mn;
    }

    const float om = __shfl_xor(m, 32, 64);
    const float M = fmaxf(m, om);
    const float sc = __expf(m - M);
    const float os = __shfl_xor(s, 32, 64);
    const float osc = __expf(om - M);
    const float S = s * sc + os * osc;
    float A[8];
#pragma unroll
    for (int k = 0; k < 8; ++k) {
        const float oa = __shfl_xor(a[k], 32, 64);
        A[k] = a[k] * sc + oa * osc;
    }

    const int pidx = b * 32 + slab * 4 + wave;
    if (lane == 0) { pm[pidx] = M; ps[pidx] = S; }
    if (lane < 32) {
        const float4 s0 = {A[0], A[1], A[2], A[3]};
        const float4 s1 = {A[4], A[5], A[6], A[7]};
        *(float4*)(pws + (size_t)pidx * 256 + li * 8) = s0;
        *(float4*)(pws + (size_t)pidx * 256 + li * 8 + 4) = s1;
    }
}

// Combine 32 partials into attended[t] for batch b (per-thread scalar).
DEVI float combine_att(const float* __restrict__ pm, const float* __restrict__ ps,
                       const float* __restrict__ pws, int b, int t) {
    float M = -1e30f;
#pragma unroll
    for (int p = 0; p < 32; ++p) M = fmaxf(M, pm[b * 32 + p]);
    float den = 0.f, acc = 0.f;
#pragma unroll
    for (int p = 0; p < 32; ++p) {
        const float sc = __expf(pm[b * 32 + p] - M);
        den += ps[b * 32 + p] * sc;
        acc += pws[(size_t)(b * 32 + p) * 256 + t] * sc;
    }
    return acc / den;
}

// ---------------------------------------------------------------------------
// Fused LSTM: attention-combine + gates GEMV + cell update (round-5 verified).
// ---------------------------------------------------------------------------
__global__ __launch_bounds__(256) void lstm_fused(const void* __restrict__ W_ih,
                                                  const void* __restrict__ W_hh,
                                                  const void* __restrict__ b_ih,
                                                  const void* __restrict__ b_hh,
                                                  const float* __restrict__ pm,
                                                  const float* __restrict__ ps,
                                                  const float* __restrict__ pws,
                                                  const float* __restrict__ qin,
                                                  float* __restrict__ qout,
                                                  float* __restrict__ ct,
                                                  const int* __restrict__ flag,
                                                  int it, void* __restrict__ out) {
    const bool f32 = (*flag) != 0;
    const int b = blockIdx.x >> 3, slab = blockIdx.x & 7;
    const int tid = threadIdx.x;
    const int lane = tid & 63, g = tid >> 6;  // wave = gate

    __shared__ float att[256];
    __shared__ float gsh[4][32];
    att[tid] = combine_att(pm, ps, pws, b, tid);
    __syncthreads();

    float sv[8];
    if (lane < 32) {
#pragma unroll
        for (int j = 0; j < 8; ++j) sv[j] = att[lane * 8 + j];
    } else if (it != 0) {
        const float* p = qin + b * 256 + (lane - 32) * 8;
        const float4 a = *(const float4*)p, c = *(const float4*)(p + 4);
        sv[0] = a.x; sv[1] = a.y; sv[2] = a.z; sv[3] = a.w;
        sv[4] = c.x; sv[5] = c.y; sv[6] = c.z; sv[7] = c.w;
    } else {
#pragma unroll
        for (int j = 0; j < 8; ++j) sv[j] = 0.f;
    }

    float r = 0.f;
#pragma unroll 4
    for (int oo = 0; oo < 32; ++oo) {
        const int o = g * 256 + slab * 32 + oo;
        float w[8];
        if (lane < 32) load8(W_ih, (size_t)o * 256 + lane * 8, f32, w);
        else load8(W_hh, (size_t)o * 256 + (lane - 32) * 8, f32, w);
        float p = 0.f;
#pragma unroll
        for (int j = 0; j < 8; ++j) p += w[j] * sv[j];
#pragma unroll
        for (int off = 32; off; off >>= 1) p += __shfl_xor(p, off, 64);
        if (lane == oo) r = p;
    }
    if (lane < 32) gsh[g][lane] = r;
    __syncthreads();

    if (tid < 32) {
        const int hidx = slab * 32 + tid;
        const float gi = gsh[0][tid] + loadS(b_ih, hidx, f32) + loadS(b_hh, hidx, f32);
        const float gf = gsh[1][tid] + loadS(b_ih, 256 + hidx, f32) +
                         loadS(b_hh, 256 + hidx, f32);
        const float gg = gsh[2][tid] + loadS(b_ih, 512 + hidx, f32) +
                         loadS(b_hh, 512 + hidx, f32);
        const float go = gsh[3][tid] + loadS(b_ih, 768 + hidx, f32) +
                         loadS(b_hh, 768 + hidx, f32);
        const float iv = sigmoidf(gi);
        const float fv = sigmoidf(gf);
        const float gv = tanh_fast(gg);
        const float ov = sigmoidf(go);
        const float cprev = (it != 0) ? ct[b * 256 + hidx] : 0.f;
        const float c = fv * cprev + iv * gv;
        const float h = ov * tanh_fast(c);
        ct[b * 256 + hidx] = c;
        qout[b * 256 + hidx] = h;
        if (it == 4) {
            if (f32) {
                float* o = (float*)out;
                o[b * 512 + hidx] = att[hidx];
                o[b * 512 + 256 + hidx] = h;
            } else {
                u16* o = (u16*)out;
                o[b * 512 + hidx] = f2b(att[hidx]);
                o[b * 512 + 256 + hidx] = f2b(h);
            }
        }
    }
}

// ---------------------------------------------------------------------------
extern "C" void kernel_launch(void* const* d_in, const int* in_sizes, int n_in,
                              void* d_out, int out_size, void* d_ws, size_t ws_size,
                              hipStream_t stream) {
    const void* state = d_in[0];
    const int* length = (const int*)d_in[1];
    const void* W1 = d_in[2];
    const void* b1 = d_in[3];
    const void* W2 = d_in[4];
    const void* b2 = d_in[5];
    const void* W3 = d_in[6];
    const void* b3 = d_in[7];
    const void* W_ih = d_in[8];
    const void* W_hh = d_in[9];
    const void* b_ih = d_in[10];
    const void* b_hh = d_in[11];

    if (ws_size < ((size_t)80 << 20)) return;  // diagnostic: absmax = 0.2988

    u16* emb = (u16*)d_ws;                     // 131072*256 bf16 = 67.1 MB
    u16* Wc = emb + (size_t)131072 * 256;      // 458752 u16 (bf16 MLP weights)
    float* qt0 = (float*)(Wc + 458752);        // 128*256 f32 (uninit ok; it0 guarded)
    float* ctb = qt0 + 32768;                  // 128*256 f32 (uninit ok; it0 guarded)
    float* qt1 = ctb + 32768;                  // 128*256 f32
    int* flag = (int*)(qt1 + 32768);           // 1 int (+3 pad)
    int* lists = flag + 4;                     // 2 groups x 512 ints
    int* counts = lists + 2048;                // 2 ints (+pad to 16)
    float* pm = (float*)(counts + 16);         // [4096]
    float* ps = pm + 4096;                     // [4096]
    float* pws = ps + 4096;                    // [4096,256] f32 (4 MB)

    // ONE setup dispatch: weight convert + 128-row live lists + dtype flag.
    hipLaunchKernelGGL(setup_all, dim3(899), dim3(512), 0, stream, W1, W2, W3, Wc,
                       length, 2, 512, 65536, lists, counts, flag);

    // ONE fused MLP dispatch: state -> emb; 1024 blocks (128-row tiles).
    hipLaunchKernelGGL(mlp_fused, dim3(1024), dim3(512), 0, stream, state, Wc,
                       b1, b2, b3, emb, lists, counts, flag);

    float* qswap[2] = {qt0, qt1};
    for (int it = 0; it < 5; ++it) {
        float* qin = qswap[it & 1];
        float* qout = qswap[(it & 1) ^ 1];
        hipLaunchKernelGGL(attn_fused, dim3(1024), dim3(256), 0, stream, emb, length, qin,
                           pm, ps, pws, it);
        hipLaunchKernelGGL(lstm_fused, dim3(1024), dim3(256), 0, stream, W_ih, W_hh,
                           b_ih, b_hh, pm, ps, pws, qin, qout, ctb, flag, it, d_out);
    }
}